// Round 1
// baseline (1615.111 us; speedup 1.0000x reference)
//
#include <hip/hip_runtime.h>
#include <hip/hip_bf16.h>

#define HW 65536   // 256*256
#define HDIM 256

// ---------------------------------------------------------------------------
// Tiled fp32 GEMM for 1x1 conv: Y[b, co, p] = sum_c W[co,c] * Xshift[b,c,p] (+bias, relu, resid)
// G = spatial-shift group size (CI/5), 0 = no shift.
// ---------------------------------------------------------------------------
template<int CI, int G, bool RELU, bool RESID>
__global__ __launch_bounds__(256) void conv_gemm(
    const float* __restrict__ X, const float* __restrict__ W,
    const float* __restrict__ bias, const float* __restrict__ R,
    float* __restrict__ Y, int Co)
{
    constexpr int TK = 12;   // divides 180 and 360
    constexpr int TC = 64;   // cout tile
    constexpr int TP = 64;   // pixel tile (divides 256 -> one h row per block)

    __shared__ float Wt[TK][TC];
    __shared__ float Xt[TK][TP];

    const int b   = blockIdx.z;
    const int p0  = blockIdx.x * TP;
    const int co0 = blockIdx.y * TC;
    const int tid = threadIdx.x;
    const int ro  = (tid >> 4) * 4;   // 0..60 cout sub-row
    const int cp  = (tid & 15) * 4;   // 0..60 pixel sub-col
    const int h   = p0 >> 8;          // whole block shares one image row

    float acc[4][4] = {};
    const float* Xb = X + (size_t)b * CI * HW;

    for (int kt = 0; kt < CI; kt += TK) {
        // stage W tile [TK][TC]
        #pragma unroll
        for (int e = tid; e < TK * TC; e += 256) {
            int k = e / TC, c = e % TC;
            int co = co0 + c;
            Wt[k][c] = (co < Co) ? W[(size_t)co * CI + kt + k] : 0.f;
        }
        // stage X tile [TK][TP] with fused spatial shift
        #pragma unroll
        for (int e = tid; e < TK * TP; e += 256) {
            int k = e / TP, pl = e % TP;
            int c = kt + k;
            int pg = p0 + pl;
            const float* Xc = Xb + (size_t)c * HW;
            float v;
            if (G == 0) {
                v = Xc[pg];
            } else {
                int grp = c / G;
                int w = pg & 255;
                if (grp == 0)      v = (w == 255) ? 0.f : Xc[pg + 1];    // left
                else if (grp == 1) v = (w == 0)   ? 0.f : Xc[pg - 1];    // right
                else if (grp == 2) v = (h == 255) ? 0.f : Xc[pg + 256];  // up
                else if (grp == 3) v = (h == 0)   ? 0.f : Xc[pg - 256];  // down
                else               v = Xc[pg];
            }
            Xt[k][pl] = v;
        }
        __syncthreads();

        #pragma unroll
        for (int k = 0; k < TK; ++k) {
            float4 wv = *reinterpret_cast<const float4*>(&Wt[k][ro]);
            float4 xv = *reinterpret_cast<const float4*>(&Xt[k][cp]);
            float wa[4] = {wv.x, wv.y, wv.z, wv.w};
            float xa[4] = {xv.x, xv.y, xv.z, xv.w};
            #pragma unroll
            for (int i = 0; i < 4; ++i)
                #pragma unroll
                for (int j = 0; j < 4; ++j)
                    acc[i][j] += wa[i] * xa[j];
        }
        __syncthreads();
    }

    #pragma unroll
    for (int i = 0; i < 4; ++i) {
        int co = co0 + ro + i;
        if (co < Co) {
            float bs = bias[co];
            size_t base = ((size_t)b * Co + co) * HW + p0 + cp;
            #pragma unroll
            for (int j = 0; j < 4; ++j) {
                float v = acc[i][j] + bs;
                if (RELU) v = fmaxf(v, 0.f);
                if (RESID) v += R[base + j];
                Y[base + j] = v;
            }
        }
    }
}

// ---------------------------------------------------------------------------
// BatchNorm statistics: one block per channel (360). Produces fused scale/shift.
// ---------------------------------------------------------------------------
__global__ __launch_bounds__(256) void bn_stats(
    const float* __restrict__ Z, const float* __restrict__ g,
    const float* __restrict__ bb, float* __restrict__ scale,
    float* __restrict__ shiftc)
{
    const int c = blockIdx.x;
    const int tid = threadIdx.x;
    float s = 0.f, sq = 0.f;
    for (int b = 0; b < 2; ++b) {
        const float* zc = Z + ((size_t)b * 360 + c) * HW;
        for (int p = tid; p < HW; p += 256) {
            float v = zc[p];
            s += v; sq += v * v;
        }
    }
    __shared__ float rs[256], rq[256];
    rs[tid] = s; rq[tid] = sq;
    __syncthreads();
    for (int st = 128; st > 0; st >>= 1) {
        if (tid < st) { rs[tid] += rs[tid + st]; rq[tid] += rq[tid + st]; }
        __syncthreads();
    }
    if (tid == 0) {
        const float invN = 1.f / (2.f * HW);
        float mean = rs[0] * invN;
        float var  = rq[0] * invN - mean * mean;
        float istd = 1.f / sqrtf(var + 1e-5f);
        float sc = g[c] * istd;
        scale[c]  = sc;
        shiftc[c] = bb[c] - mean * sc;
    }
}

// ---------------------------------------------------------------------------
// Windowed self-attention for one chunk. BN-apply fused into the load.
// One thread = one (window, head, row n). q/v staged in LDS per ws^2 group.
// ---------------------------------------------------------------------------
template<int WS>
__global__ __launch_bounds__(256) void attn_kernel(
    const float* __restrict__ Z, const float* __restrict__ scale,
    const float* __restrict__ shiftc, float* __restrict__ O, int chunk)
{
    constexpr int NP  = WS * WS;        // positions per window
    constexpr int GPB = 256 / NP;       // (window,head) groups per block
    constexpr int SH  = WS / 2;         // roll shift
    constexpr int NW  = HDIM / WS;      // windows per image dim

    __shared__ float qs[256 * 11];
    __shared__ float vs[256 * 11];

    const int tid = threadIdx.x;
    const int lg  = tid / NP;
    const int n   = tid % NP;
    const int gidx = blockIdx.x * GPB + lg;

    const int head = gidx % 6;
    const int win  = gidx / 6;
    const int wcol = win % NW;
    const int tmp  = win / NW;
    const int wrow = tmp % NW;
    const int b    = tmp / NW;

    const int i = n / WS, j = n % WS;
    const int h = (wrow * WS + i + SH) & 255;
    const int w = (wcol * WS + j + SH) & 255;
    const int pix = (h << 8) | w;

    const int cq = chunk * 120 + head * 10;
    const int cv = cq + 60;
    const size_t zb = (size_t)b * 360 * HW;

    float q[10];
    float* qrow = &qs[tid * 11];
    float* vrow = &vs[tid * 11];
    #pragma unroll
    for (int c = 0; c < 10; ++c) {
        float qc = Z[zb + (size_t)(cq + c) * HW + pix] * scale[cq + c] + shiftc[cq + c];
        float vc = Z[zb + (size_t)(cv + c) * HW + pix] * scale[cv + c] + shiftc[cv + c];
        q[c] = qc; qrow[c] = qc; vrow[c] = vc;
    }
    __syncthreads();

    const float* qg = &qs[(lg * NP) * 11];
    const float* vg = &vs[(lg * NP) * 11];

    // pass 1: row max of logits
    float mx = -1e30f;
    for (int m = 0; m < NP; ++m) {
        float d = 0.f;
        #pragma unroll
        for (int c = 0; c < 10; ++c) d += q[c] * qg[m * 11 + c];
        mx = fmaxf(mx, d);
    }
    // pass 2: exp-sum and PV accumulate
    float s = 0.f;
    float o[10] = {};
    for (int m = 0; m < NP; ++m) {
        float d = 0.f;
        #pragma unroll
        for (int c = 0; c < 10; ++c) d += q[c] * qg[m * 11 + c];
        float e = __expf(d - mx);
        s += e;
        #pragma unroll
        for (int c = 0; c < 10; ++c) o[c] += e * vg[m * 11 + c];
    }
    const float inv = 1.f / s;
    const int co0 = chunk * 60 + head * 10;
    const size_t ob = (size_t)b * 180 * HW;
    #pragma unroll
    for (int c = 0; c < 10; ++c)
        O[ob + (size_t)(co0 + c) * HW + pix] = o[c] * inv;
}

// ---------------------------------------------------------------------------
extern "C" void kernel_launch(void* const* d_in, const int* in_sizes, int n_in,
                              void* d_out, int out_size, void* d_ws, size_t ws_size,
                              hipStream_t stream)
{
    const float* x     = (const float*)d_in[0];
    const float* w0    = (const float*)d_in[1];
    const float* b0    = (const float*)d_in[2];
    const float* w1    = (const float*)d_in[3];
    const float* b1    = (const float*)d_in[4];
    const float* w_in  = (const float*)d_in[5];
    const float* b_in  = (const float*)d_in[6];
    const float* bn_g  = (const float*)d_in[7];
    const float* bn_b  = (const float*)d_in[8];
    const float* w_out = (const float*)d_in[9];
    const float* b_out = (const float*)d_in[10];
    float* out = (float*)d_out;

    // workspace layout (fp32): A = 2*360*HW (y then z), Cb = 2*180*HW (attn out)
    float* A      = (float*)d_ws;
    float* Cb     = A + (size_t)2 * 360 * HW;
    float* scale  = Cb + (size_t)2 * 180 * HW;
    float* shiftc = scale + 360;

    dim3 blk(256);

    // conv1: y = relu(W0 @ shift(x) + b0)            [2,360,HW] -> A
    conv_gemm<180, 36, true,  false><<<dim3(1024, 6, 2), blk, 0, stream>>>(x,  w0,   b0,   nullptr, A,   360);
    // conv2: x1 = W1 @ shift(y) + b1 + x             [2,180,HW] -> out (x1 temp)
    conv_gemm<360, 72, false, true ><<<dim3(1024, 3, 2), blk, 0, stream>>>(A,  w1,   b1,   x,       out, 180);
    // conv3: z = W_in @ x1 + b_in                    [2,360,HW] -> A
    conv_gemm<180, 0,  false, false><<<dim3(1024, 6, 2), blk, 0, stream>>>(out, w_in, b_in, nullptr, A,   360);
    // BN statistics -> fused scale/shift
    bn_stats<<<dim3(360), blk, 0, stream>>>(A, bn_g, bn_b, scale, shiftc);
    // window attention (BN applied on load), chunks 0/1/2 with ws = 2/4/8
    attn_kernel<2><<<dim3(3072), blk, 0, stream>>>(A, scale, shiftc, Cb, 0);
    attn_kernel<4><<<dim3(3072), blk, 0, stream>>>(A, scale, shiftc, Cb, 1);
    attn_kernel<8><<<dim3(3072), blk, 0, stream>>>(A, scale, shiftc, Cb, 2);
    // conv4: out = W_out @ attn + b_out + x1
    conv_gemm<180, 0,  false, true ><<<dim3(1024, 3, 2), blk, 0, stream>>>(Cb, w_out, b_out, out, out, 180);
}

// Round 4
// 1082.498 us; speedup vs baseline: 1.4920x; 1.4920x over previous
//
#include <hip/hip_runtime.h>
#include <hip/hip_bf16.h>

#define HWSZ 65536   // 256*256

typedef unsigned short u16;
typedef __bf16 bf16x4 __attribute__((ext_vector_type(4)));
typedef __bf16 bf16x8 __attribute__((ext_vector_type(8)));
typedef float f32x4 __attribute__((ext_vector_type(4)));
typedef unsigned short u16x4 __attribute__((ext_vector_type(4)));

// integer round-to-nearest-even fp32 -> bf16
__device__ inline u16 f2bf(float f) {
    unsigned int x = __builtin_bit_cast(unsigned int, f);
    unsigned int r = x + 0x7FFFu + ((x >> 16) & 1u);
    return (u16)(r >> 16);
}

// ---------------------------------------------------------------------------
// MFMA conv GEMM, fp32 NCHW in/out, bf16 LDS tiles.
// Y[b, co, p] = sum_c W[co,c] * Xshift[b,c,p] (+bias, relu, resid)
// G = spatial-shift group size (CI/5), 0 = no shift.
// Tiles: 64 co x 64 pixels x 32 k. 4 waves (2 co-halves x 2 pixel-halves).
// ---------------------------------------------------------------------------
template<int CI, int G, bool RELU, bool RESID>
__global__ __launch_bounds__(256) void conv_mfma(
    const float* __restrict__ X, const float* __restrict__ W,
    const float* __restrict__ bias, const float* __restrict__ R,
    float* __restrict__ Y, int Co)
{
    constexpr int BK = 32;
    constexpr int LDKW = 40;   // Wt row stride (u16), 16B-aligned rows
    constexpr int LDKX = 36;   // Xt row stride (u16), 8B-aligned rows
    __shared__ u16 Wt[64 * LDKW];
    __shared__ u16 Xt[64 * LDKX];

    const int tid = threadIdx.x;
    const int b   = blockIdx.z;
    const int p0  = blockIdx.x * 64;       // pixel base within batch [0,65536)
    const int co0 = blockIdx.y * 64;
    const int h   = p0 >> 8;               // all 64 pixels share this row
    const int w0  = p0 & 255;

    const int lane = tid & 63;
    const int wid  = tid >> 6;
    const int wm = wid >> 1, wn = wid & 1;
    const int lr = lane & 15, lg = lane >> 4;

    f32x4 acc[2][2] = {};
    const float* Xb = X + (size_t)b * CI * HWSZ;

    for (int kt = 0; kt < CI; kt += BK) {
        // ---- stage W tile: 64 co-rows x 32 k, bf16, natural [co][k]
        {
            const int m  = tid >> 2;        // 0..63
            const int kq = tid & 3;         // 0..3  (8 k each)
            const int k  = kt + kq * 8;
            const int co = co0 + m;
            u16x4 lo = {0, 0, 0, 0}, hi = {0, 0, 0, 0};
            if (co < Co) {
                const float* wr = W + (size_t)co * CI + k;
                #pragma unroll
                for (int j = 0; j < 4; ++j) {
                    if (k + j     < CI) lo[j] = f2bf(wr[j]);
                    if (k + 4 + j < CI) hi[j] = f2bf(wr[4 + j]);
                }
            }
            *(u16x4*)&Wt[m * LDKW + kq * 8]     = lo;
            *(u16x4*)&Wt[m * LDKW + kq * 8 + 4] = hi;
        }
        // ---- stage X tile transposed: [pixel n][k], fused spatial shift.
        // unit u -> (n = u&63, k4 = u>>6): 4 channels of one pixel, u16x4 write.
        #pragma unroll
        for (int it = 0; it < 2; ++it) {
            const int u  = tid + it * 256;
            const int n  = u & 63;
            const int k4 = u >> 6;          // 0..7
            u16 vals[4];
            #pragma unroll
            for (int j = 0; j < 4; ++j) {
                const int c = kt + k4 * 4 + j;
                float v = 0.f;
                if (c < CI) {
                    int dh = 0, dw = 0;
                    if (G > 0) {
                        const int g = c / G;
                        if      (g == 0) dw = 1;
                        else if (g == 1) dw = -1;
                        else if (g == 2) dh = 1;
                        else if (g == 3) dh = -1;
                    }
                    const int hh = h + dh;
                    const int wp = w0 + n + dw;
                    if (hh >= 0 && hh < 256 && wp >= 0 && wp < 256)
                        v = Xb[(size_t)c * HWSZ + hh * 256 + wp];
                }
                vals[j] = f2bf(v);
            }
            *(u16x4*)&Xt[n * LDKX + k4 * 4] = (u16x4){vals[0], vals[1], vals[2], vals[3]};
        }
        __syncthreads();

        // ---- fragments + MFMA
        const u16* wbase = &Wt[(wm * 32 + lr) * LDKW + lg * 8];
        const u16* xbase = &Xt[(wn * 32 + lr) * LDKX + lg * 8];
        bf16x8 af[2], bfr[2];
        #pragma unroll
        for (int mf = 0; mf < 2; ++mf)
            af[mf] = *reinterpret_cast<const bf16x8*>(wbase + mf * 16 * LDKW);
        #pragma unroll
        for (int nf = 0; nf < 2; ++nf) {
            const u16* xp = xbase + nf * 16 * LDKX;
            bf16x4 x0 = *reinterpret_cast<const bf16x4*>(xp);
            bf16x4 x1 = *reinterpret_cast<const bf16x4*>(xp + 4);
            bf16x8 bb;
            bb[0] = x0[0]; bb[1] = x0[1]; bb[2] = x0[2]; bb[3] = x0[3];
            bb[4] = x1[0]; bb[5] = x1[1]; bb[6] = x1[2]; bb[7] = x1[3];
            bfr[nf] = bb;
        }
        #pragma unroll
        for (int mf = 0; mf < 2; ++mf)
            #pragma unroll
            for (int nf = 0; nf < 2; ++nf)
                acc[mf][nf] = __builtin_amdgcn_mfma_f32_16x16x32_bf16(
                    af[mf], bfr[nf], acc[mf][nf], 0, 0, 0);
        __syncthreads();
    }

    // ---- epilogue: D row (co) = (lane>>4)*4 + reg, col (pixel) = lane&15
    #pragma unroll
    for (int mf = 0; mf < 2; ++mf) {
        const int co_b = co0 + wm * 32 + mf * 16 + lg * 4;
        if (co_b >= Co) continue;
        #pragma unroll
        for (int nf = 0; nf < 2; ++nf) {
            const int p = p0 + wn * 32 + nf * 16 + lr;
            #pragma unroll
            for (int r = 0; r < 4; ++r) {
                float v = acc[mf][nf][r] + bias[co_b + r];
                if (RELU) v = fmaxf(v, 0.f);
                const size_t idx = ((size_t)(b * Co + co_b + r)) * HWSZ + p;
                if (RESID) v += R[idx];
                Y[idx] = v;
            }
        }
    }
}

// ---------------------------------------------------------------------------
// BatchNorm statistics: one block per channel (360). (verbatim round 1)
// ---------------------------------------------------------------------------
__global__ __launch_bounds__(256) void bn_stats(
    const float* __restrict__ Z, const float* __restrict__ g,
    const float* __restrict__ bb, float* __restrict__ scale,
    float* __restrict__ shiftc)
{
    const int c = blockIdx.x;
    const int tid = threadIdx.x;
    float s = 0.f, sq = 0.f;
    for (int b = 0; b < 2; ++b) {
        const float* zc = Z + ((size_t)b * 360 + c) * HWSZ;
        for (int p = tid; p < HWSZ; p += 256) {
            float v = zc[p];
            s += v; sq += v * v;
        }
    }
    __shared__ float rs[256], rq[256];
    rs[tid] = s; rq[tid] = sq;
    __syncthreads();
    for (int st = 128; st > 0; st >>= 1) {
        if (tid < st) { rs[tid] += rs[tid + st]; rq[tid] += rq[tid + st]; }
        __syncthreads();
    }
    if (tid == 0) {
        const float invN = 1.f / (2.f * HWSZ);
        float mean = rs[0] * invN;
        float var  = rq[0] * invN - mean * mean;
        float istd = 1.f / sqrtf(var + 1e-5f);
        float sc = g[c] * istd;
        scale[c]  = sc;
        shiftc[c] = bb[c] - mean * sc;
    }
}

// ---------------------------------------------------------------------------
// Windowed self-attention for one chunk. (verbatim round 1)
// ---------------------------------------------------------------------------
template<int WS>
__global__ __launch_bounds__(256) void attn_kernel(
    const float* __restrict__ Z, const float* __restrict__ scale,
    const float* __restrict__ shiftc, float* __restrict__ O, int chunk)
{
    constexpr int NP  = WS * WS;
    constexpr int GPB = 256 / NP;
    constexpr int SH  = WS / 2;
    constexpr int NW  = 256 / WS;

    __shared__ float qs[256 * 11];
    __shared__ float vs[256 * 11];

    const int tid = threadIdx.x;
    const int lg  = tid / NP;
    const int n   = tid % NP;
    const int gidx = blockIdx.x * GPB + lg;

    const int head = gidx % 6;
    const int win  = gidx / 6;
    const int wcol = win % NW;
    const int tmp  = win / NW;
    const int wrow = tmp % NW;
    const int b    = tmp / NW;

    const int i = n / WS, j = n % WS;
    const int h = (wrow * WS + i + SH) & 255;
    const int w = (wcol * WS + j + SH) & 255;
    const int pix = (h << 8) | w;

    const int cq = chunk * 120 + head * 10;
    const int cv = cq + 60;
    const size_t zb = (size_t)b * 360 * HWSZ;

    float q[10];
    float* qrow = &qs[tid * 11];
    float* vrow = &vs[tid * 11];
    #pragma unroll
    for (int c = 0; c < 10; ++c) {
        float qc = Z[zb + (size_t)(cq + c) * HWSZ + pix] * scale[cq + c] + shiftc[cq + c];
        float vc = Z[zb + (size_t)(cv + c) * HWSZ + pix] * scale[cv + c] + shiftc[cv + c];
        q[c] = qc; qrow[c] = qc; vrow[c] = vc;
    }
    __syncthreads();

    const float* qg = &qs[(lg * NP) * 11];
    const float* vg = &vs[(lg * NP) * 11];

    float mx = -1e30f;
    for (int m = 0; m < NP; ++m) {
        float d = 0.f;
        #pragma unroll
        for (int c = 0; c < 10; ++c) d += q[c] * qg[m * 11 + c];
        mx = fmaxf(mx, d);
    }
    float s = 0.f;
    float o[10] = {};
    for (int m = 0; m < NP; ++m) {
        float d = 0.f;
        #pragma unroll
        for (int c = 0; c < 10; ++c) d += q[c] * qg[m * 11 + c];
        float e = __expf(d - mx);
        s += e;
        #pragma unroll
        for (int c = 0; c < 10; ++c) o[c] += e * vg[m * 11 + c];
    }
    const float inv = 1.f / s;
    const int co0 = chunk * 60 + head * 10;
    const size_t ob = (size_t)b * 180 * HWSZ;
    #pragma unroll
    for (int c = 0; c < 10; ++c)
        O[ob + (size_t)(co0 + c) * HWSZ + pix] = o[c] * inv;
}

// ---------------------------------------------------------------------------
extern "C" void kernel_launch(void* const* d_in, const int* in_sizes, int n_in,
                              void* d_out, int out_size, void* d_ws, size_t ws_size,
                              hipStream_t stream)
{
    const float* x     = (const float*)d_in[0];
    const float* w0    = (const float*)d_in[1];
    const float* b0    = (const float*)d_in[2];
    const float* w1    = (const float*)d_in[3];
    const float* b1    = (const float*)d_in[4];
    const float* w_in  = (const float*)d_in[5];
    const float* b_in  = (const float*)d_in[6];
    const float* bn_g  = (const float*)d_in[7];
    const float* bn_b  = (const float*)d_in[8];
    const float* w_out = (const float*)d_in[9];
    const float* b_out = (const float*)d_in[10];
    float* out = (float*)d_out;

    // workspace layout (fp32, identical to round 1):
    float* A      = (float*)d_ws;                       // [2,360,HW] (y then z)
    float* Cb     = A + (size_t)2 * 360 * HWSZ;         // [2,180,HW] attn out
    float* scale  = Cb + (size_t)2 * 180 * HWSZ;
    float* shiftc = scale + 360;

    dim3 blk(256);

    // conv1: y = relu(W0 @ shift(x) + b0)            -> A
    conv_mfma<180, 36, true,  false><<<dim3(1024, 6, 2), blk, 0, stream>>>(x,   w0,    b0,    nullptr, A,   360);
    // conv2: x1 = W1 @ shift(y) + b1 + x             -> out (temp)
    conv_mfma<360, 72, false, true ><<<dim3(1024, 3, 2), blk, 0, stream>>>(A,   w1,    b1,    x,       out, 180);
    // conv3: z = W_in @ x1 + b_in                    -> A
    conv_mfma<180, 0,  false, false><<<dim3(1024, 6, 2), blk, 0, stream>>>(out, w_in,  b_in,  nullptr, A,   360);
    // BN statistics -> fused scale/shift
    bn_stats<<<dim3(360), blk, 0, stream>>>(A, bn_g, bn_b, scale, shiftc);
    // window attention, chunks 0/1/2 with ws = 2/4/8
    attn_kernel<2><<<dim3(3072), blk, 0, stream>>>(A, scale, shiftc, Cb, 0);
    attn_kernel<4><<<dim3(3072), blk, 0, stream>>>(A, scale, shiftc, Cb, 1);
    attn_kernel<8><<<dim3(3072), blk, 0, stream>>>(A, scale, shiftc, Cb, 2);
    // conv4: out = W_out @ attn + b_out + x1
    conv_mfma<180, 0,  false, true ><<<dim3(1024, 3, 2), blk, 0, stream>>>(Cb,  w_out, b_out, out,     out, 180);
}

// Round 5
// 626.049 us; speedup vs baseline: 2.5798x; 1.7291x over previous
//
#include <hip/hip_runtime.h>
#include <hip/hip_bf16.h>

#define HWSZ 65536   // 256*256
#define NPIX 131072  // 2 * HWSZ

typedef unsigned short u16;
typedef __bf16 bf16x8 __attribute__((ext_vector_type(8)));
typedef float f32x4 __attribute__((ext_vector_type(4)));
typedef unsigned short u16x2 __attribute__((ext_vector_type(2)));
typedef unsigned short u16x4 __attribute__((ext_vector_type(4)));
typedef unsigned short u16x8 __attribute__((ext_vector_type(8)));

// integer round-to-nearest-even fp32 -> bf16
__device__ inline u16 f2bf(float f) {
    unsigned int x = __builtin_bit_cast(unsigned int, f);
    unsigned int r = x + 0x7FFFu + ((x >> 16) & 1u);
    return (u16)(r >> 16);
}
__device__ inline float bf2f(u16 u) {
    unsigned int x = ((unsigned int)u) << 16;
    return __builtin_bit_cast(float, x);
}

// ---------------------------------------------------------------------------
// Weight prep: fp32 [R][C] -> bf16 zero-padded [RP][CP].
// w0:360x180->384x192, w_in:360x180->384x192, w1:180x360->192x384,
// w_out:180x180->192x192.  grid 288*256 = 73728 threads.
// ---------------------------------------------------------------------------
__global__ __launch_bounds__(256) void prep_w(
    const float* __restrict__ w0, const float* __restrict__ w1,
    const float* __restrict__ wi, const float* __restrict__ wo,
    u16* __restrict__ W0p, u16* __restrict__ W1p,
    u16* __restrict__ Wip, u16* __restrict__ Wop)
{
    const int i = blockIdx.x * 256 + threadIdx.x;   // < 73728
    {   // 384 x 192 regions
        const int r = i / 192, c = i % 192;
        const bool ok = (r < 360) && (c < 180);
        W0p[i] = ok ? f2bf(w0[r * 180 + c]) : (u16)0;
        Wip[i] = ok ? f2bf(wi[r * 180 + c]) : (u16)0;
    }
    {   // 192 x 384 region
        const int r = i / 384, c = i % 384;
        W1p[i] = (r < 180 && c < 360) ? f2bf(w1[r * 360 + c]) : (u16)0;
    }
    if (i < 36864) {   // 192 x 192 region
        const int r = i / 192, c = i % 192;
        Wop[i] = (r < 180 && c < 180) ? f2bf(wo[r * 180 + c]) : (u16)0;
    }
}

// ---------------------------------------------------------------------------
// Full-M MFMA conv GEMM, NCHW layouts.
// Y[b, co, p] = sum_c W[co,c] * Xshift[b,c,p] (+bias, relu, resid fp32)
// Block: 256 threads (4 waves), all CO_PAD output channels x 64 pixels.
// Wave wid owns rows [wid*CO_PAD/4, +CO_PAD/4) -> MFRAG m-frags x 4 n-frags.
// X staged once per K-step for the whole block (X read once per conv).
// ---------------------------------------------------------------------------
template<int CI, int CO, int CO_PAD, int G, bool INF32, bool RELU, bool RESID, bool OUTBF>
__global__ __launch_bounds__(256) void conv_fullm(
    const void* __restrict__ Xv, const u16* __restrict__ Wp,
    const float* __restrict__ bias, const float* __restrict__ R,
    void* __restrict__ Yv)
{
    constexpr int NK     = (CI + 31) / 32;
    constexpr int CI_PAD = NK * 32;
    constexpr int MFRAG  = CO_PAD / 64;     // m-frags per wave
    constexpr int LDK    = 40;              // LDS row stride (u16)

    __shared__ u16 Wt[CO_PAD * LDK];
    __shared__ u16 Xt[64 * LDK];

    const int tid  = threadIdx.x;
    const int p0   = blockIdx.x * 64;        // flat pixel base (both batches)
    const int b    = p0 >> 16;
    const int pix0 = p0 & 65535;
    const int h    = pix0 >> 8;
    const int w0c  = pix0 & 255;

    const int lane = tid & 63;
    const int wid  = tid >> 6;
    const int lr = lane & 15, lg = lane >> 4;

    const float* Xf = (const float*)Xv + (size_t)b * CI * HWSZ;
    const u16*   Xh = (const u16*)Xv   + (size_t)b * CI * HWSZ;

    f32x4 acc[MFRAG][4] = {};

    for (int kt = 0; kt < CI_PAD; kt += 32) {
        // ---- stage W tile: CO_PAD rows x 32 k, unconditional 16B copies
        #pragma unroll
        for (int e0 = 0; e0 < CO_PAD * 4; e0 += 256) {
            const int e = e0 + tid;
            const int m = e >> 2, kq = e & 3;
            u16x8 wv = *(const u16x8*)&Wp[(size_t)m * CI_PAD + kt + kq * 8];
            *(u16x8*)&Wt[m * LDK + kq * 8] = wv;
        }
        // ---- stage X tile transposed [pixel][k], fused spatial shift
        #pragma unroll
        for (int it = 0; it < 2; ++it) {
            const int u  = tid + it * 256;
            const int n  = u & 63;
            const int k4 = u >> 6;           // 0..7
            u16 vals[4];
            #pragma unroll
            for (int j = 0; j < 4; ++j) {
                const int c = kt + k4 * 4 + j;
                u16 hv = 0;
                if (c < CI) {
                    int dh = 0, dw = 0;
                    if (G > 0) {
                        const int g = c / G;
                        if      (g == 0) dw = 1;
                        else if (g == 1) dw = -1;
                        else if (g == 2) dh = 1;
                        else if (g == 3) dh = -1;
                    }
                    const int hh = h + dh;
                    const int wp = w0c + n + dw;
                    if (hh >= 0 && hh < 256 && wp >= 0 && wp < 256) {
                        const size_t off = (size_t)c * HWSZ + hh * 256 + wp;
                        if (INF32) hv = f2bf(Xf[off]);
                        else       hv = Xh[off];
                    }
                }
                vals[j] = hv;
            }
            *(u16x4*)&Xt[n * LDK + k4 * 4] = (u16x4){vals[0], vals[1], vals[2], vals[3]};
        }
        __syncthreads();

        // ---- fragments + MFMA (24 or 12 per wave per K-step)
        const u16* wb_ = &Wt[(wid * (CO_PAD / 4) + lr) * LDK + lg * 8];
        const u16* xb_ = &Xt[lr * LDK + lg * 8];
        bf16x8 af[MFRAG], bfr[4];
        #pragma unroll
        for (int mf = 0; mf < MFRAG; ++mf)
            af[mf] = *(const bf16x8*)(wb_ + mf * 16 * LDK);
        #pragma unroll
        for (int nf = 0; nf < 4; ++nf)
            bfr[nf] = *(const bf16x8*)(xb_ + nf * 16 * LDK);
        #pragma unroll
        for (int mf = 0; mf < MFRAG; ++mf)
            #pragma unroll
            for (int nf = 0; nf < 4; ++nf)
                acc[mf][nf] = __builtin_amdgcn_mfma_f32_16x16x32_bf16(
                    af[mf], bfr[nf], acc[mf][nf], 0, 0, 0);
        __syncthreads();
    }

    // ---- epilogue: co = base + lg*4 + r, pixel col = lr
    #pragma unroll
    for (int mf = 0; mf < MFRAG; ++mf) {
        const int co_b = wid * (CO_PAD / 4) + mf * 16 + lg * 4;
        if (co_b >= CO) continue;
        #pragma unroll
        for (int nf = 0; nf < 4; ++nf) {
            const int p = pix0 + nf * 16 + lr;
            #pragma unroll
            for (int r = 0; r < 4; ++r) {
                const int co = co_b + r;
                float v = acc[mf][nf][r] + bias[co];
                if (RELU) v = fmaxf(v, 0.f);
                const size_t idx = ((size_t)(b * CO + co)) * HWSZ + p;
                if (RESID) v += R[idx];
                if (OUTBF) ((u16*)Yv)[idx] = f2bf(v);
                else       ((float*)Yv)[idx] = v;
            }
        }
    }
}

// ---------------------------------------------------------------------------
// BatchNorm statistics from bf16 z: one block per channel (360).
// ---------------------------------------------------------------------------
__global__ __launch_bounds__(256) void bn_stats16(
    const u16* __restrict__ Z, const float* __restrict__ g,
    const float* __restrict__ bb, float* __restrict__ scale,
    float* __restrict__ shiftc)
{
    const int c = blockIdx.x;
    const int tid = threadIdx.x;
    float s = 0.f, sq = 0.f;
    for (int b = 0; b < 2; ++b) {
        const u16* zc = Z + ((size_t)b * 360 + c) * HWSZ;
        for (int p = tid * 4; p < HWSZ; p += 1024) {
            u16x4 t = *(const u16x4*)&zc[p];
            #pragma unroll
            for (int j = 0; j < 4; ++j) {
                float v = bf2f(t[j]);
                s += v; sq += v * v;
            }
        }
    }
    __shared__ float rs[256], rq[256];
    rs[tid] = s; rq[tid] = sq;
    __syncthreads();
    for (int st = 128; st > 0; st >>= 1) {
        if (tid < st) { rs[tid] += rs[tid + st]; rq[tid] += rq[tid + st]; }
        __syncthreads();
    }
    if (tid == 0) {
        const float invN = 1.f / (float)NPIX;
        float mean = rs[0] * invN;
        float var  = rq[0] * invN - mean * mean;
        float istd = 1.f / sqrtf(var + 1e-5f);
        float sc = g[c] * istd;
        scale[c]  = sc;
        shiftc[c] = bb[c] - mean * sc;
    }
}

// ---------------------------------------------------------------------------
// Windowed self-attention (bf16 NCHW z in, bf16 NCHW out, BN fused on load).
// Structure verbatim from round 4 (proven); only dtypes changed.
// ---------------------------------------------------------------------------
template<int WS>
__global__ __launch_bounds__(256) void attn16(
    const u16* __restrict__ Z, const float* __restrict__ scale,
    const float* __restrict__ shiftc, u16* __restrict__ O, int chunk)
{
    constexpr int NP  = WS * WS;
    constexpr int GPB = 256 / NP;
    constexpr int SH  = WS / 2;
    constexpr int NW  = 256 / WS;

    __shared__ float qs[256 * 11];
    __shared__ float vs[256 * 11];

    const int tid = threadIdx.x;
    const int lg  = tid / NP;
    const int n   = tid % NP;
    const int gidx = blockIdx.x * GPB + lg;

    const int head = gidx % 6;
    const int win  = gidx / 6;
    const int wcol = win % NW;
    const int tmp  = win / NW;
    const int wrow = tmp % NW;
    const int b    = tmp / NW;

    const int i = n / WS, j = n % WS;
    const int h = (wrow * WS + i + SH) & 255;
    const int w = (wcol * WS + j + SH) & 255;
    const int pix = (h << 8) | w;

    const int cq = chunk * 120 + head * 10;
    const int cv = cq + 60;
    const size_t zb = (size_t)b * 360 * HWSZ;

    float q[10];
    float* qrow = &qs[tid * 11];
    float* vrow = &vs[tid * 11];
    #pragma unroll
    for (int c = 0; c < 10; ++c) {
        float qc = bf2f(Z[zb + (size_t)(cq + c) * HWSZ + pix]) * scale[cq + c] + shiftc[cq + c];
        float vc = bf2f(Z[zb + (size_t)(cv + c) * HWSZ + pix]) * scale[cv + c] + shiftc[cv + c];
        q[c] = qc; qrow[c] = qc; vrow[c] = vc;
    }
    __syncthreads();

    const float* qg = &qs[(lg * NP) * 11];
    const float* vg = &vs[(lg * NP) * 11];

    float mx = -1e30f;
    for (int m = 0; m < NP; ++m) {
        float d = 0.f;
        #pragma unroll
        for (int c = 0; c < 10; ++c) d += q[c] * qg[m * 11 + c];
        mx = fmaxf(mx, d);
    }
    float s = 0.f;
    float o[10] = {};
    for (int m = 0; m < NP; ++m) {
        float d = 0.f;
        #pragma unroll
        for (int c = 0; c < 10; ++c) d += q[c] * qg[m * 11 + c];
        float e = __expf(d - mx);
        s += e;
        #pragma unroll
        for (int c = 0; c < 10; ++c) o[c] += e * vg[m * 11 + c];
    }
    const float inv = 1.f / s;
    const int co0 = chunk * 60 + head * 10;
    const size_t ob = (size_t)b * 180 * HWSZ;
    #pragma unroll
    for (int c = 0; c < 10; ++c)
        O[ob + (size_t)(co0 + c) * HWSZ + pix] = f2bf(o[c] * inv);
}

// ---------------------------------------------------------------------------
extern "C" void kernel_launch(void* const* d_in, const int* in_sizes, int n_in,
                              void* d_out, int out_size, void* d_ws, size_t ws_size,
                              hipStream_t stream)
{
    const float* x     = (const float*)d_in[0];
    const float* w0    = (const float*)d_in[1];
    const float* b0    = (const float*)d_in[2];
    const float* w1    = (const float*)d_in[3];
    const float* b1    = (const float*)d_in[4];
    const float* w_in  = (const float*)d_in[5];
    const float* b_in  = (const float*)d_in[6];
    const float* bn_g  = (const float*)d_in[7];
    const float* bn_b  = (const float*)d_in[8];
    const float* w_out = (const float*)d_in[9];
    const float* b_out = (const float*)d_in[10];
    float* out = (float*)d_out;

    // workspace layout (bf16 NCHW intermediates; x1 fp32 lives in d_out)
    u16* y   = (u16*)d_ws;                     // [2,360,HW] bf16
    u16* z   = y  + (size_t)360 * NPIX;        // [2,360,HW] bf16
    u16* ab  = z  + (size_t)360 * NPIX;        // [2,180,HW] bf16
    u16* W0p = ab + (size_t)180 * NPIX;        // 384x192
    u16* Wip = W0p + 384 * 192;                // 384x192
    u16* W1p = Wip + 384 * 192;                // 192x384
    u16* Wop = W1p + 192 * 384;                // 192x192
    float* scale  = (float*)(Wop + 192 * 192);
    float* shiftc = scale + 360;

    dim3 blk(256);

    prep_w<<<dim3(288), blk, 0, stream>>>(w0, w1, w_in, w_out, W0p, W1p, Wip, Wop);

    // conv1: y = relu(W0 @ shift(x) + b0)         x fp32 -> y bf16
    conv_fullm<180, 360, 384, 36, true,  true,  false, true >
        <<<dim3(2048), blk, 0, stream>>>(x, W0p, b0, nullptr, y);
    // conv2: x1 = W1 @ shift(y) + b1 + x          y bf16, resid x fp32 -> d_out fp32
    conv_fullm<360, 180, 192, 72, false, false, true,  false>
        <<<dim3(2048), blk, 0, stream>>>(y, W1p, b1, x, out);
    // conv3: z = W_in @ x1 + b_in                 x1 fp32 (d_out) -> z bf16
    conv_fullm<180, 360, 384, 0,  true,  false, false, true >
        <<<dim3(2048), blk, 0, stream>>>(out, Wip, b_in, nullptr, z);
    // BN statistics -> fused scale/shift
    bn_stats16<<<dim3(360), blk, 0, stream>>>(z, bn_g, bn_b, scale, shiftc);
    // window attention, chunks 0/1/2 with ws = 2/4/8 -> ab bf16
    attn16<2><<<dim3(3072), blk, 0, stream>>>(z, scale, shiftc, ab, 0);
    attn16<4><<<dim3(3072), blk, 0, stream>>>(z, scale, shiftc, ab, 1);
    attn16<8><<<dim3(3072), blk, 0, stream>>>(z, scale, shiftc, ab, 2);
    // conv4: out = W_out @ ab + b_out + x1        ab bf16, resid x1 fp32 -> d_out fp32
    conv_fullm<180, 180, 192, 0,  false, false, true,  false>
        <<<dim3(2048), blk, 0, stream>>>(ab, Wop, b_out, out, out);
}

// Round 6
// 486.552 us; speedup vs baseline: 3.3195x; 1.2867x over previous
//
#include <hip/hip_runtime.h>
#include <hip/hip_bf16.h>
#include <type_traits>

#define HWSZ 65536   // 256*256
#define NPIX 131072  // 2 * HWSZ

typedef unsigned short u16;
typedef __bf16 bf16x8 __attribute__((ext_vector_type(8)));
typedef float f32x4 __attribute__((ext_vector_type(4)));
typedef unsigned short u16x4 __attribute__((ext_vector_type(4)));

// integer round-to-nearest-even fp32 -> bf16
__device__ inline u16 f2bf(float f) {
    unsigned int x = __builtin_bit_cast(unsigned int, f);
    unsigned int r = x + 0x7FFFu + ((x >> 16) & 1u);
    return (u16)(r >> 16);
}
__device__ inline float bf2f(u16 u) {
    unsigned int x = ((unsigned int)u) << 16;
    return __builtin_bit_cast(float, x);
}

// ---------------------------------------------------------------------------
// Weight prep: fp32 [R][C] -> bf16 zero-padded [RP][CP].  (verbatim round 5)
// w0:360x180->384x192, w_in:360x180->384x192, w1:180x360->192x384,
// w_out:180x180->192x192.  grid 288*256 = 73728 threads.
// ---------------------------------------------------------------------------
__global__ __launch_bounds__(256) void prep_w(
    const float* __restrict__ w0, const float* __restrict__ w1,
    const float* __restrict__ wi, const float* __restrict__ wo,
    u16* __restrict__ W0p, u16* __restrict__ W1p,
    u16* __restrict__ Wip, u16* __restrict__ Wop)
{
    const int i = blockIdx.x * 256 + threadIdx.x;   // < 73728
    {   // 384 x 192 regions
        const int r = i / 192, c = i % 192;
        const bool ok = (r < 360) && (c < 180);
        W0p[i] = ok ? f2bf(w0[r * 180 + c]) : (u16)0;
        Wip[i] = ok ? f2bf(wi[r * 180 + c]) : (u16)0;
    }
    {   // 192 x 384 region
        const int r = i / 384, c = i % 384;
        W1p[i] = (r < 180 && c < 360) ? f2bf(w1[r * 360 + c]) : (u16)0;
    }
    if (i < 36864) {   // 192 x 192 region
        const int r = i / 192, c = i % 192;
        Wop[i] = (r < 180 && c < 180) ? f2bf(wo[r * 180 + c]) : (u16)0;
    }
}

// ---------------------------------------------------------------------------
// Pipelined MFMA conv GEMM, NCHW layouts.
// Y[b, co, p] = sum_c W[co,c] * Xshift[b,c,p] (+bias, relu, resid)
// Block: 256 threads (4 waves) x BM=192 co-rows x 64 pixels.
// W fragments loaded directly from global (L2-hot, no LDS).
// X: register-prefetch + double-buffered LDS, ONE barrier per K-step.
// RES: 0 none, 1 fp32, 2 bf16.  IN32: X is fp32 (else bf16).
// ---------------------------------------------------------------------------
template<int CI, int CO, int G, bool IN32, bool RELU, int RES, bool OUTBF>
__global__ __launch_bounds__(256, 4) void conv_v3(
    const void* __restrict__ Xv, const u16* __restrict__ Wp,
    const float* __restrict__ bias, const void* __restrict__ Rv,
    void* __restrict__ Yv)
{
    constexpr int CI_PAD = ((CI + 31) / 32) * 32;
    constexpr int NSTEP  = CI_PAD / 32;
    constexpr int LDK    = 40;     // u16 row stride (80B): frag reads ~2-way
    using LT = typename std::conditional<IN32, float, u16>::type;

    __shared__ u16 Xt[2][64 * LDK];   // 2 x 5120 B

    const int tid  = threadIdx.x;
    const int p0   = blockIdx.x * 64;
    const int b    = p0 >> 16;
    const int pix0 = p0 & 65535;
    const int h    = pix0 >> 8;
    const int w0c  = pix0 & 255;
    const int lane = tid & 63, wid = tid >> 6;
    const int lr = lane & 15, lg = lane >> 4;
    const int co_wave = blockIdx.y * 192 + wid * 48;

    const float* Xf = (const float*)Xv + (size_t)b * CI * HWSZ;
    const u16*   Xh = (const u16*)Xv   + (size_t)b * CI * HWSZ;

    const int xn  = tid & 63;   // pixel within tile this thread stages
    const int k4a = tid >> 6;   // base k-quad (0..3); also handles k4a+4

    auto loadX = [&](int kt, LT (&r)[8]) {
        #pragma unroll
        for (int it = 0; it < 2; ++it) {
            const int k4 = k4a + it * 4;
            #pragma unroll
            for (int j = 0; j < 4; ++j) {
                const int c = kt + k4 * 4 + j;
                LT v = (LT)0;
                if (c < CI) {
                    int dh = 0, dw = 0;
                    if (G > 0) {
                        const int g = c / G;
                        if      (g == 0) dw = 1;
                        else if (g == 1) dw = -1;
                        else if (g == 2) dh = 1;
                        else if (g == 3) dh = -1;
                    }
                    const int hh = h + dh;
                    const int wp = w0c + xn + dw;
                    if (hh >= 0 && hh < 256 && wp >= 0 && wp < 256) {
                        const size_t off = (size_t)c * HWSZ + hh * 256 + wp;
                        if constexpr (IN32) v = Xf[off];
                        else                v = Xh[off];
                    }
                }
                r[it * 4 + j] = v;
            }
        }
    };

    auto loadW = [&](int kt, bf16x8 (&a)[3]) {
        #pragma unroll
        for (int mf = 0; mf < 3; ++mf)
            a[mf] = *(const bf16x8*)&Wp[(size_t)(co_wave + mf * 16 + lr) * CI_PAD + kt + lg * 8];
    };

    auto writeLDS = [&](LT (&r)[8], int buf) {
        #pragma unroll
        for (int it = 0; it < 2; ++it) {
            u16x4 v;
            #pragma unroll
            for (int j = 0; j < 4; ++j) {
                if constexpr (IN32) v[j] = f2bf(r[it * 4 + j]);
                else                v[j] = r[it * 4 + j];
            }
            *(u16x4*)&Xt[buf][xn * LDK + (k4a + it * 4) * 4] = v;
        }
    };

    f32x4 acc[3][4] = {};
    LT raw[2][8];
    bf16x8 af[2][3];

    loadX(0, raw[0]);
    loadW(0, af[0]);
    writeLDS(raw[0], 0);

    #pragma unroll
    for (int s = 0; s < NSTEP; ++s) {
        const int cur = s & 1, nxt = cur ^ 1;
        __syncthreads();                      // Xt[cur] ready for all waves
        if (s + 1 < NSTEP) {                  // prefetch next step (regs only)
            loadX((s + 1) * 32, raw[nxt]);
            loadW((s + 1) * 32, af[nxt]);
        }
        bf16x8 bfr[4];
        #pragma unroll
        for (int nf = 0; nf < 4; ++nf)
            bfr[nf] = *(const bf16x8*)&Xt[cur][(nf * 16 + lr) * LDK + lg * 8];
        #pragma unroll
        for (int mf = 0; mf < 3; ++mf)
            #pragma unroll
            for (int nf = 0; nf < 4; ++nf)
                acc[mf][nf] = __builtin_amdgcn_mfma_f32_16x16x32_bf16(
                    af[cur][mf], bfr[nf], acc[mf][nf], 0, 0, 0);
        if (s + 1 < NSTEP)                    // write other buffer: no race
            writeLDS(raw[nxt], nxt);
    }

    // ---- epilogue: co = co_wave + mf*16 + lg*4 + r, pixel col = lr
    const float* Rf = (const float*)Rv;
    const u16*   Rh = (const u16*)Rv;
    #pragma unroll
    for (int mf = 0; mf < 3; ++mf) {
        const int co_b = co_wave + mf * 16 + lg * 4;
        if (co_b >= CO) continue;
        #pragma unroll
        for (int nf = 0; nf < 4; ++nf) {
            const int p = pix0 + nf * 16 + lr;
            #pragma unroll
            for (int r = 0; r < 4; ++r) {
                const int co = co_b + r;
                float v = acc[mf][nf][r] + bias[co];
                if (RELU) v = fmaxf(v, 0.f);
                const size_t idx = ((size_t)(b * CO + co)) * HWSZ + p;
                if (RES == 1) v += Rf[idx];
                if (RES == 2) v += bf2f(Rh[idx]);
                if (OUTBF) ((u16*)Yv)[idx] = f2bf(v);
                else       ((float*)Yv)[idx] = v;
            }
        }
    }
}

// ---------------------------------------------------------------------------
// BatchNorm statistics from bf16 z: one block per channel. (verbatim round 5)
// ---------------------------------------------------------------------------
__global__ __launch_bounds__(256) void bn_stats16(
    const u16* __restrict__ Z, const float* __restrict__ g,
    const float* __restrict__ bb, float* __restrict__ scale,
    float* __restrict__ shiftc)
{
    const int c = blockIdx.x;
    const int tid = threadIdx.x;
    float s = 0.f, sq = 0.f;
    for (int b = 0; b < 2; ++b) {
        const u16* zc = Z + ((size_t)b * 360 + c) * HWSZ;
        for (int p = tid * 4; p < HWSZ; p += 1024) {
            u16x4 t = *(const u16x4*)&zc[p];
            #pragma unroll
            for (int j = 0; j < 4; ++j) {
                float v = bf2f(t[j]);
                s += v; sq += v * v;
            }
        }
    }
    __shared__ float rs[256], rq[256];
    rs[tid] = s; rq[tid] = sq;
    __syncthreads();
    for (int st = 128; st > 0; st >>= 1) {
        if (tid < st) { rs[tid] += rs[tid + st]; rq[tid] += rq[tid + st]; }
        __syncthreads();
    }
    if (tid == 0) {
        const float invN = 1.f / (float)NPIX;
        float mean = rs[0] * invN;
        float var  = rq[0] * invN - mean * mean;
        float istd = 1.f / sqrtf(var + 1e-5f);
        float sc = g[c] * istd;
        scale[c]  = sc;
        shiftc[c] = bb[c] - mean * sc;
    }
}

// ---------------------------------------------------------------------------
// Windowed self-attention (bf16 NCHW in/out, BN fused). (verbatim round 5)
// ---------------------------------------------------------------------------
template<int WS>
__global__ __launch_bounds__(256) void attn16(
    const u16* __restrict__ Z, const float* __restrict__ scale,
    const float* __restrict__ shiftc, u16* __restrict__ O, int chunk)
{
    constexpr int NP  = WS * WS;
    constexpr int GPB = 256 / NP;
    constexpr int SH  = WS / 2;
    constexpr int NW  = 256 / WS;

    __shared__ float qs[256 * 11];
    __shared__ float vs[256 * 11];

    const int tid = threadIdx.x;
    const int lg  = tid / NP;
    const int n   = tid % NP;
    const int gidx = blockIdx.x * GPB + lg;

    const int head = gidx % 6;
    const int win  = gidx / 6;
    const int wcol = win % NW;
    const int tmp  = win / NW;
    const int wrow = tmp % NW;
    const int b    = tmp / NW;

    const int i = n / WS, j = n % WS;
    const int h = (wrow * WS + i + SH) & 255;
    const int w = (wcol * WS + j + SH) & 255;
    const int pix = (h << 8) | w;

    const int cq = chunk * 120 + head * 10;
    const int cv = cq + 60;
    const size_t zb = (size_t)b * 360 * HWSZ;

    float q[10];
    float* qrow = &qs[tid * 11];
    float* vrow = &vs[tid * 11];
    #pragma unroll
    for (int c = 0; c < 10; ++c) {
        float qc = bf2f(Z[zb + (size_t)(cq + c) * HWSZ + pix]) * scale[cq + c] + shiftc[cq + c];
        float vc = bf2f(Z[zb + (size_t)(cv + c) * HWSZ + pix]) * scale[cv + c] + shiftc[cv + c];
        q[c] = qc; qrow[c] = qc; vrow[c] = vc;
    }
    __syncthreads();

    const float* qg = &qs[(lg * NP) * 11];
    const float* vg = &vs[(lg * NP) * 11];

    float mx = -1e30f;
    for (int m = 0; m < NP; ++m) {
        float d = 0.f;
        #pragma unroll
        for (int c = 0; c < 10; ++c) d += q[c] * qg[m * 11 + c];
        mx = fmaxf(mx, d);
    }
    float s = 0.f;
    float o[10] = {};
    for (int m = 0; m < NP; ++m) {
        float d = 0.f;
        #pragma unroll
        for (int c = 0; c < 10; ++c) d += q[c] * qg[m * 11 + c];
        float e = __expf(d - mx);
        s += e;
        #pragma unroll
        for (int c = 0; c < 10; ++c) o[c] += e * vg[m * 11 + c];
    }
    const float inv = 1.f / s;
    const int co0 = chunk * 60 + head * 10;
    const size_t ob = (size_t)b * 180 * HWSZ;
    #pragma unroll
    for (int c = 0; c < 10; ++c)
        O[ob + (size_t)(co0 + c) * HWSZ + pix] = f2bf(o[c] * inv);
}

// ---------------------------------------------------------------------------
extern "C" void kernel_launch(void* const* d_in, const int* in_sizes, int n_in,
                              void* d_out, int out_size, void* d_ws, size_t ws_size,
                              hipStream_t stream)
{
    const float* x     = (const float*)d_in[0];
    const float* w0    = (const float*)d_in[1];
    const float* b0    = (const float*)d_in[2];
    const float* w1    = (const float*)d_in[3];
    const float* b1    = (const float*)d_in[4];
    const float* w_in  = (const float*)d_in[5];
    const float* b_in  = (const float*)d_in[6];
    const float* bn_g  = (const float*)d_in[7];
    const float* bn_b  = (const float*)d_in[8];
    const float* w_out = (const float*)d_in[9];
    const float* b_out = (const float*)d_in[10];
    float* out = (float*)d_out;

    // workspace (bf16 NCHW): y and z share (y dead after conv2)
    u16* y   = (u16*)d_ws;                     // [2,360,HW] bf16 (later z)
    u16* x1b = y   + (size_t)360 * NPIX;       // [2,180,HW] bf16
    u16* ab  = x1b + (size_t)180 * NPIX;       // [2,180,HW] bf16
    u16* W0p = ab  + (size_t)180 * NPIX;       // 384x192
    u16* Wip = W0p + 384 * 192;                // 384x192
    u16* W1p = Wip + 384 * 192;                // 192x384
    u16* Wop = W1p + 192 * 384;                // 192x192
    float* scale  = (float*)(Wop + 192 * 192);
    float* shiftc = scale + 360;
    u16* z = y;

    dim3 blk(256);

    prep_w<<<dim3(288), blk, 0, stream>>>(w0, w1, w_in, w_out, W0p, W1p, Wip, Wop);

    // conv1: y = relu(W0 @ shift(x) + b0)        x fp32 -> y bf16
    conv_v3<180, 360, 36, true,  true,  0, true >
        <<<dim3(2048, 2), blk, 0, stream>>>(x, W0p, b0, nullptr, y);
    // conv2: x1 = W1 @ shift(y) + b1 + x         y bf16, resid x fp32 -> x1b bf16
    conv_v3<360, 180, 72, false, false, 1, true >
        <<<dim3(2048, 1), blk, 0, stream>>>(y, W1p, b1, x, x1b);
    // conv3: z = W_in @ x1 + b_in                x1b bf16 -> z bf16 (aliases y)
    conv_v3<180, 360, 0,  false, false, 0, true >
        <<<dim3(2048, 2), blk, 0, stream>>>(x1b, Wip, b_in, nullptr, z);
    // BN statistics -> fused scale/shift
    bn_stats16<<<dim3(360), blk, 0, stream>>>(z, bn_g, bn_b, scale, shiftc);
    // window attention, chunks 0/1/2 with ws = 2/4/8 -> ab bf16
    attn16<2><<<dim3(3072), blk, 0, stream>>>(z, scale, shiftc, ab, 0);
    attn16<4><<<dim3(3072), blk, 0, stream>>>(z, scale, shiftc, ab, 1);
    attn16<8><<<dim3(3072), blk, 0, stream>>>(z, scale, shiftc, ab, 2);
    // conv4: out = W_out @ ab + b_out + x1       ab bf16, resid x1b -> out fp32
    conv_v3<180, 180, 0,  false, false, 2, false>
        <<<dim3(2048, 1), blk, 0, stream>>>(ab, Wop, b_out, x1b, out);
}

// Round 7
// 435.670 us; speedup vs baseline: 3.7072x; 1.1168x over previous
//
#include <hip/hip_runtime.h>
#include <hip/hip_bf16.h>

#define HWSZ 65536   // 256*256
#define NPIX 131072  // 2 * HWSZ

typedef unsigned short u16;
typedef __bf16 bf16x8 __attribute__((ext_vector_type(8)));
typedef float f32x4 __attribute__((ext_vector_type(4)));
typedef unsigned short u16x2 __attribute__((ext_vector_type(2)));
typedef unsigned short u16x4 __attribute__((ext_vector_type(4)));
typedef unsigned short u16x8 __attribute__((ext_vector_type(8)));

// integer round-to-nearest-even fp32 -> bf16
__device__ inline u16 f2bf(float f) {
    unsigned int x = __builtin_bit_cast(unsigned int, f);
    unsigned int r = x + 0x7FFFu + ((x >> 16) & 1u);
    return (u16)(r >> 16);
}
__device__ inline float bf2f(u16 u) {
    unsigned int x = ((unsigned int)u) << 16;
    return __builtin_bit_cast(float, x);
}

// ---------------------------------------------------------------------------
// Weight prep: fp32 [R][C] -> bf16 zero-padded [RP][CP].  (verbatim round 5/6)
// ---------------------------------------------------------------------------
__global__ __launch_bounds__(256) void prep_w(
    const float* __restrict__ w0, const float* __restrict__ w1,
    const float* __restrict__ wi, const float* __restrict__ wo,
    u16* __restrict__ W0p, u16* __restrict__ W1p,
    u16* __restrict__ Wip, u16* __restrict__ Wop)
{
    const int i = blockIdx.x * 256 + threadIdx.x;   // < 73728
    {   // 384 x 192 regions
        const int r = i / 192, c = i % 192;
        const bool ok = (r < 360) && (c < 180);
        W0p[i] = ok ? f2bf(w0[r * 180 + c]) : (u16)0;
        Wip[i] = ok ? f2bf(wi[r * 180 + c]) : (u16)0;
    }
    {   // 192 x 384 region
        const int r = i / 384, c = i % 384;
        W1p[i] = (r < 180 && c < 360) ? f2bf(w1[r * 360 + c]) : (u16)0;
    }
    if (i < 36864) {   // 192 x 192 region
        const int r = i / 192, c = i % 192;
        Wop[i] = (r < 180 && c < 180) ? f2bf(wo[r * 180 + c]) : (u16)0;
    }
}

// ---------------------------------------------------------------------------
// Pipelined MFMA conv GEMM (round-6 skeleton).
// Block: 256 threads (4 waves) x 192 co-rows x 64 pixels. W frags from global.
// X: register-prefetch + double-buffered LDS, ONE barrier per K-step.
// INM: 0 = fp32 NCHW input, 1 = bf16 NHWC (stride XSTR).
// RES: 0 none, 1 fp32 NCHW, 2 bf16 NHWC stride 192.
// OUTM: 0 fp32 NCHW, 1 bf16 NHWC (stride OSTR).
// ---------------------------------------------------------------------------
template<int CI, int CO, int G, int INM, int XSTR, bool RELU, int RES, int OUTM, int OSTR>
__global__ __launch_bounds__(256, 4) void conv_v4(
    const void* __restrict__ Xv, const u16* __restrict__ Wp,
    const float* __restrict__ bias, const void* __restrict__ Rv,
    void* __restrict__ Yv)
{
    constexpr int CI_PAD = ((CI + 31) / 32) * 32;
    constexpr int NSTEP  = CI_PAD / 32;
    constexpr int LDK    = 40;     // u16 row stride

    __shared__ u16 Xt[2][64 * LDK];

    const int tid  = threadIdx.x;
    const int p0   = blockIdx.x * 64;      // global flat pixel base (incl. batch)
    const int b    = p0 >> 16;
    const int pix0 = p0 & 65535;
    const int h    = pix0 >> 8;
    const int w0c  = pix0 & 255;
    const int lane = tid & 63, wid = tid >> 6;
    const int lr = lane & 15, lg = lane >> 4;
    const int co_wave = blockIdx.y * 192 + wid * 48;

    const float* Xf = (const float*)Xv + (size_t)b * CI * HWSZ;
    const u16*   Xh = (const u16*)Xv;      // NHWC: batch folded into pixel id

    const int xn  = tid & 63;   // pixel within tile this thread stages
    const int k4a = tid >> 6;   // base k-quad (0..3); also handles k4a+4

    auto loadX = [&](int kt, u16x4 (&r)[2]) {
        #pragma unroll
        for (int it = 0; it < 2; ++it) {
            const int k4 = k4a + it * 4;
            const int c0 = kt + k4 * 4;
            u16x4 v = {0, 0, 0, 0};
            if (c0 < CI) {     // quads never straddle CI (4 | CI)
                int dh = 0, dw = 0;
                if (G > 0) {   // 4 | G: shift is quad-uniform
                    const int g = c0 / G;
                    if      (g == 0) dw = 1;
                    else if (g == 1) dw = -1;
                    else if (g == 2) dh = 1;
                    else if (g == 3) dh = -1;
                }
                const int hh = h + dh;
                const int wp = w0c + xn + dw;
                if (hh >= 0 && hh < 256 && wp >= 0 && wp < 256) {
                    if constexpr (INM == 1) {
                        const size_t pg = (size_t)((b << 16) | (hh << 8) | wp);
                        v = *(const u16x4*)&Xh[pg * XSTR + c0];
                    } else {
                        const float* xs = Xf + (size_t)c0 * HWSZ + hh * 256 + wp;
                        #pragma unroll
                        for (int j = 0; j < 4; ++j) v[j] = f2bf(xs[(size_t)j * HWSZ]);
                    }
                }
            }
            r[it] = v;
        }
    };

    auto loadW = [&](int kt, bf16x8 (&a)[3]) {
        #pragma unroll
        for (int mf = 0; mf < 3; ++mf)
            a[mf] = *(const bf16x8*)&Wp[(size_t)(co_wave + mf * 16 + lr) * CI_PAD + kt + lg * 8];
    };

    auto writeLDS = [&](u16x4 (&r)[2], int buf) {
        *(u16x4*)&Xt[buf][xn * LDK + k4a * 4]       = r[0];
        *(u16x4*)&Xt[buf][xn * LDK + (k4a + 4) * 4] = r[1];
    };

    f32x4 acc[3][4] = {};
    u16x4 raw[2][2];
    bf16x8 af[2][3];

    loadX(0, raw[0]);
    loadW(0, af[0]);
    writeLDS(raw[0], 0);

    #pragma unroll
    for (int s = 0; s < NSTEP; ++s) {
        const int cur = s & 1, nxt = cur ^ 1;
        __syncthreads();                      // Xt[cur] ready for all waves
        if (s + 1 < NSTEP) {                  // prefetch next step (regs only)
            loadX((s + 1) * 32, raw[nxt]);
            loadW((s + 1) * 32, af[nxt]);
        }
        bf16x8 bfr[4];
        #pragma unroll
        for (int nf = 0; nf < 4; ++nf)
            bfr[nf] = *(const bf16x8*)&Xt[cur][(nf * 16 + lr) * LDK + lg * 8];
        #pragma unroll
        for (int mf = 0; mf < 3; ++mf)
            #pragma unroll
            for (int nf = 0; nf < 4; ++nf)
                acc[mf][nf] = __builtin_amdgcn_mfma_f32_16x16x32_bf16(
                    af[cur][mf], bfr[nf], acc[mf][nf], 0, 0, 0);
        if (s + 1 < NSTEP)                    // write other buffer: no race
            writeLDS(raw[nxt], nxt);
    }

    // ---- epilogue: co = co_wave + mf*16 + lg*4 + r, pixel col = lr
    const float* Rf = (const float*)Rv;
    const u16*   Rh = (const u16*)Rv;
    #pragma unroll
    for (int mf = 0; mf < 3; ++mf) {
        const int co_b = co_wave + mf * 16 + lg * 4;
        if (co_b >= CO) continue;
        #pragma unroll
        for (int nf = 0; nf < 4; ++nf) {
            const int pl = pix0 + nf * 16 + lr;         // pixel within batch
            const size_t pg = (size_t)p0 + nf * 16 + lr; // global flat pixel
            float v[4];
            #pragma unroll
            for (int r = 0; r < 4; ++r) {
                v[r] = acc[mf][nf][r] + bias[co_b + r];
                if (RELU) v[r] = fmaxf(v[r], 0.f);
            }
            if (RES == 1) {
                #pragma unroll
                for (int r = 0; r < 4; ++r)
                    v[r] += Rf[((size_t)(b * CO + co_b + r)) * HWSZ + pl];
            }
            if (RES == 2) {
                u16x4 rr = *(const u16x4*)&Rh[pg * 192 + co_b];
                #pragma unroll
                for (int r = 0; r < 4; ++r) v[r] += bf2f(rr[r]);
            }
            if (OUTM == 1) {
                u16x4 o;
                #pragma unroll
                for (int r = 0; r < 4; ++r) o[r] = f2bf(v[r]);
                *(u16x4*)&((u16*)Yv)[pg * OSTR + co_b] = o;
            } else {
                #pragma unroll
                for (int r = 0; r < 4; ++r)
                    ((float*)Yv)[((size_t)(b * CO + co_b + r)) * HWSZ + pl] = v[r];
            }
        }
    }
}

// ---------------------------------------------------------------------------
// BN stats on NHWC zt, stage 1: per-stripe partial sums (deterministic).
// grid 128; block handles 1024 pixels; lanes 0..44 own channel octets.
// part layout: [512 stripes][45 octets][16 floats (8 sum, 8 sumsq)]
// ---------------------------------------------------------------------------
__global__ __launch_bounds__(256) void bn_part(const u16* __restrict__ zt,
                                               float* __restrict__ part)
{
    const int tid = threadIdx.x;
    const int oc  = tid & 63;        // channel octet (0..44 active)
    const int pp  = tid >> 6;        // 0..3
    if (oc >= 45) return;
    const int stripe = blockIdx.x * 4 + pp;
    const int pb = blockIdx.x * 1024 + pp;
    float s[8] = {}, q[8] = {};
    for (int i = 0; i < 256; ++i) {
        const int p = pb + i * 4;
        u16x8 t = *(const u16x8*)&zt[(size_t)p * 384 + oc * 8];
        #pragma unroll
        for (int j = 0; j < 8; ++j) {
            float v = bf2f(t[j]);
            s[j] += v; q[j] += v * v;
        }
    }
    float* pr = part + ((size_t)stripe * 45 + oc) * 16;
    #pragma unroll
    for (int j = 0; j < 8; ++j) { pr[j] = s[j]; pr[8 + j] = q[j]; }
}

// BN stats, stage 2: reduce 512 stripes -> fused scale/shift. grid 45.
__global__ __launch_bounds__(256) void bn_fin(const float* __restrict__ part,
                                              const float* __restrict__ g,
                                              const float* __restrict__ bb,
                                              float* __restrict__ sc,
                                              float* __restrict__ sh)
{
    const int oc = blockIdx.x;   // 0..44
    const int t  = threadIdx.x;
    const float* p1 = part + ((size_t)t * 45 + oc) * 16;
    const float* p2 = part + ((size_t)(t + 256) * 45 + oc) * 16;
    float v[16];
    #pragma unroll
    for (int k = 0; k < 16; ++k) v[k] = p1[k] + p2[k];
    #pragma unroll
    for (int k = 0; k < 16; ++k)
        for (int m = 32; m; m >>= 1) v[k] += __shfl_xor(v[k], m, 64);
    __shared__ float red[4][16];
    if ((t & 63) == 0) {
        #pragma unroll
        for (int k = 0; k < 16; ++k) red[t >> 6][k] = v[k];
    }
    __syncthreads();
    if (t == 0) {
        const float invN = 1.f / (float)NPIX;
        #pragma unroll
        for (int j = 0; j < 8; ++j) {
            const int c = oc * 8 + j;
            float su = red[0][j] + red[1][j] + red[2][j] + red[3][j];
            float sq = red[0][8+j] + red[1][8+j] + red[2][8+j] + red[3][8+j];
            float mean = su * invN;
            float var  = sq * invN - mean * mean;
            float istd = 1.f / sqrtf(var + 1e-5f);
            float s = g[c] * istd;
            sc[c] = s;
            sh[c] = bb[c] - mean * s;
        }
    }
}

// ---------------------------------------------------------------------------
// Windowed self-attention, NHWC bf16 in (stride 384) / out (stride 192).
// Round-6 structure; loads/stores contiguous; LDS rows stride 12, float4 reads.
// ---------------------------------------------------------------------------
template<int WS>
__global__ __launch_bounds__(256) void attn_v2(
    const u16* __restrict__ zt, const float* __restrict__ scale,
    const float* __restrict__ shiftc, u16* __restrict__ ot, int chunk)
{
    constexpr int NP  = WS * WS;
    constexpr int GPB = 256 / NP;
    constexpr int SH  = WS / 2;
    constexpr int NW  = 256 / WS;

    __shared__ float qs[256 * 12];
    __shared__ float vs[256 * 12];

    const int tid = threadIdx.x;
    const int lg  = tid / NP;
    const int n   = tid % NP;
    const int gidx = blockIdx.x * GPB + lg;

    const int head = gidx % 6;
    const int win  = gidx / 6;
    const int wcol = win % NW;
    const int tmp  = win / NW;
    const int wrow = tmp % NW;
    const int b    = tmp / NW;

    const int i = n / WS, j = n % WS;
    const int hh = (wrow * WS + i + SH) & 255;
    const int ww = (wcol * WS + j + SH) & 255;
    const size_t zrow = (size_t)((b << 16) | (hh << 8) | ww) * 384;

    const int cq = chunk * 120 + head * 10;
    const int cv = cq + 60;

    float q[10];
    float* qrow = &qs[tid * 12];
    float* vrow = &vs[tid * 12];
    #pragma unroll
    for (int c2 = 0; c2 < 5; ++c2) {
        u16x2 uq = *(const u16x2*)&zt[zrow + cq + c2 * 2];
        u16x2 uv = *(const u16x2*)&zt[zrow + cv + c2 * 2];
        float q0 = bf2f(uq[0]) * scale[cq + c2 * 2]     + shiftc[cq + c2 * 2];
        float q1 = bf2f(uq[1]) * scale[cq + c2 * 2 + 1] + shiftc[cq + c2 * 2 + 1];
        float v0 = bf2f(uv[0]) * scale[cv + c2 * 2]     + shiftc[cv + c2 * 2];
        float v1 = bf2f(uv[1]) * scale[cv + c2 * 2 + 1] + shiftc[cv + c2 * 2 + 1];
        q[c2 * 2] = q0; q[c2 * 2 + 1] = q1;
        qrow[c2 * 2] = q0; qrow[c2 * 2 + 1] = q1;
        vrow[c2 * 2] = v0; vrow[c2 * 2 + 1] = v1;
    }
    qrow[10] = 0.f; qrow[11] = 0.f;
    vrow[10] = 0.f; vrow[11] = 0.f;
    __syncthreads();

    const float* qg = &qs[(lg * NP) * 12];
    const float* vg = &vs[(lg * NP) * 12];

    float mx = -1e30f;
    for (int m = 0; m < NP; ++m) {
        f32x4 a0 = *(const f32x4*)&qg[m * 12];
        f32x4 a1 = *(const f32x4*)&qg[m * 12 + 4];
        f32x4 a2 = *(const f32x4*)&qg[m * 12 + 8];
        float d = q[0]*a0[0] + q[1]*a0[1] + q[2]*a0[2] + q[3]*a0[3]
                + q[4]*a1[0] + q[5]*a1[1] + q[6]*a1[2] + q[7]*a1[3]
                + q[8]*a2[0] + q[9]*a2[1];
        mx = fmaxf(mx, d);
    }
    float s = 0.f;
    float o[10] = {};
    for (int m = 0; m < NP; ++m) {
        f32x4 a0 = *(const f32x4*)&qg[m * 12];
        f32x4 a1 = *(const f32x4*)&qg[m * 12 + 4];
        f32x4 a2 = *(const f32x4*)&qg[m * 12 + 8];
        float d = q[0]*a0[0] + q[1]*a0[1] + q[2]*a0[2] + q[3]*a0[3]
                + q[4]*a1[0] + q[5]*a1[1] + q[6]*a1[2] + q[7]*a1[3]
                + q[8]*a2[0] + q[9]*a2[1];
        float e = __expf(d - mx);
        s += e;
        f32x4 b0 = *(const f32x4*)&vg[m * 12];
        f32x4 b1 = *(const f32x4*)&vg[m * 12 + 4];
        f32x4 b2 = *(const f32x4*)&vg[m * 12 + 8];
        o[0] += e * b0[0]; o[1] += e * b0[1]; o[2] += e * b0[2]; o[3] += e * b0[3];
        o[4] += e * b1[0]; o[5] += e * b1[1]; o[6] += e * b1[2]; o[7] += e * b1[3];
        o[8] += e * b2[0]; o[9] += e * b2[1];
    }
    const float inv = 1.f / s;
    u16* orow = ot + (size_t)((b << 16) | (hh << 8) | ww) * 192 + chunk * 60 + head * 10;
    #pragma unroll
    for (int c2 = 0; c2 < 5; ++c2) {
        u16x2 ov;
        ov[0] = f2bf(o[c2 * 2] * inv);
        ov[1] = f2bf(o[c2 * 2 + 1] * inv);
        *(u16x2*)&orow[c2 * 2] = ov;
    }
}

// ---------------------------------------------------------------------------
extern "C" void kernel_launch(void* const* d_in, const int* in_sizes, int n_in,
                              void* d_out, int out_size, void* d_ws, size_t ws_size,
                              hipStream_t stream)
{
    const float* x     = (const float*)d_in[0];
    const float* w0    = (const float*)d_in[1];
    const float* b0    = (const float*)d_in[2];
    const float* w1    = (const float*)d_in[3];
    const float* b1    = (const float*)d_in[4];
    const float* w_in  = (const float*)d_in[5];
    const float* b_in  = (const float*)d_in[6];
    const float* bn_g  = (const float*)d_in[7];
    const float* bn_b  = (const float*)d_in[8];
    const float* w_out = (const float*)d_in[9];
    const float* b_out = (const float*)d_in[10];
    float* out = (float*)d_out;

    // workspace: NHWC bf16 intermediates. zt aliases y (y dead after conv2).
    u16* y   = (u16*)d_ws;                      // [131072][384] (later zt)
    u16* x1b = y   + (size_t)NPIX * 384;        // [131072][192]
    u16* ot  = x1b + (size_t)NPIX * 192;        // [131072][192]
    u16* W0p = ot  + (size_t)NPIX * 192;        // 384x192
    u16* Wip = W0p + 384 * 192;                 // 384x192
    u16* W1p = Wip + 384 * 192;                 // 192x384
    u16* Wop = W1p + 192 * 384;                 // 192x192
    float* part   = (float*)(Wop + 192 * 192);  // 512*45*16
    float* scale  = part + 512 * 45 * 16;
    float* shiftc = scale + 360;
    u16* zt = y;

    dim3 blk(256);

    prep_w<<<dim3(288), blk, 0, stream>>>(w0, w1, w_in, w_out, W0p, W1p, Wip, Wop);

    // conv1: y = relu(W0 @ shift(x) + b0)     x fp32 NCHW -> y NHWC384
    conv_v4<180, 360, 36, 0, 0,   true,  0, 1, 384>
        <<<dim3(2048, 2), blk, 0, stream>>>(x, W0p, b0, nullptr, y);
    // conv2: x1 = W1 @ shift(y) + b1 + x      y NHWC384, resid x fp32 -> x1b NHWC192
    conv_v4<360, 180, 72, 1, 384, false, 1, 1, 192>
        <<<dim3(2048, 1), blk, 0, stream>>>(y, W1p, b1, x, x1b);
    // conv3: z = W_in @ x1 + b_in             x1b NHWC192 -> zt NHWC384 (aliases y)
    conv_v4<180, 360, 0,  1, 192, false, 0, 1, 384>
        <<<dim3(2048, 2), blk, 0, stream>>>(x1b, Wip, b_in, nullptr, zt);
    // BN statistics -> fused scale/shift
    bn_part<<<dim3(128), blk, 0, stream>>>(zt, part);
    bn_fin<<<dim3(45), blk, 0, stream>>>(part, bn_g, bn_b, scale, shiftc);
    // window attention, chunks 0/1/2 with ws = 2/4/8 -> ot NHWC192
    attn_v2<2><<<dim3(3072), blk, 0, stream>>>(zt, scale, shiftc, ot, 0);
    attn_v2<4><<<dim3(3072), blk, 0, stream>>>(zt, scale, shiftc, ot, 1);
    attn_v2<8><<<dim3(3072), blk, 0, stream>>>(zt, scale, shiftc, ot, 2);
    // conv4: out = W_out @ ot + b_out + x1    ot NHWC192, resid x1b -> out fp32 NCHW
    conv_v4<180, 180, 0,  1, 192, false, 2, 0, 0>
        <<<dim3(2048, 1), blk, 0, stream>>>(ot, Wop, b_out, x1b, out);
}

// Round 8
// 423.570 us; speedup vs baseline: 3.8131x; 1.0286x over previous
//
#include <hip/hip_runtime.h>
#include <hip/hip_bf16.h>

#define HWSZ 65536   // 256*256
#define NPIX 131072  // 2 * HWSZ

typedef unsigned short u16;
typedef __bf16 bf16x8 __attribute__((ext_vector_type(8)));
typedef float f32x4 __attribute__((ext_vector_type(4)));
typedef unsigned short u16x2 __attribute__((ext_vector_type(2)));
typedef unsigned short u16x4 __attribute__((ext_vector_type(4)));
typedef unsigned short u16x8 __attribute__((ext_vector_type(8)));

// integer round-to-nearest-even fp32 -> bf16
__device__ inline u16 f2bf(float f) {
    unsigned int x = __builtin_bit_cast(unsigned int, f);
    unsigned int r = x + 0x7FFFu + ((x >> 16) & 1u);
    return (u16)(r >> 16);
}
__device__ inline float bf2f(u16 u) {
    unsigned int x = ((unsigned int)u) << 16;
    return __builtin_bit_cast(float, x);
}

// ---------------------------------------------------------------------------
// Weight prep: fp32 [R][C] -> bf16 zero-padded [RP][CP].  (verbatim r5-r7)
// ---------------------------------------------------------------------------
__global__ __launch_bounds__(256) void prep_w(
    const float* __restrict__ w0, const float* __restrict__ w1,
    const float* __restrict__ wi, const float* __restrict__ wo,
    u16* __restrict__ W0p, u16* __restrict__ W1p,
    u16* __restrict__ Wip, u16* __restrict__ Wop)
{
    const int i = blockIdx.x * 256 + threadIdx.x;   // < 73728
    {   // 384 x 192 regions
        const int r = i / 192, c = i % 192;
        const bool ok = (r < 360) && (c < 180);
        W0p[i] = ok ? f2bf(w0[r * 180 + c]) : (u16)0;
        Wip[i] = ok ? f2bf(wi[r * 180 + c]) : (u16)0;
    }
    {   // 192 x 384 region
        const int r = i / 384, c = i % 384;
        W1p[i] = (r < 180 && c < 360) ? f2bf(w1[r * 360 + c]) : (u16)0;
    }
    if (i < 36864) {   // 192 x 192 region
        const int r = i / 192, c = i % 192;
        Wop[i] = (r < 180 && c < 180) ? f2bf(wo[r * 180 + c]) : (u16)0;
    }
}

// ---------------------------------------------------------------------------
// Pipelined MFMA conv GEMM (round-7 skeleton + DEPTH-2 X prefetch).
// Block: 256 threads (4 waves) x 192 co-rows x 64 pixels. W frags from global.
// X loads for step s+2 issued at step s; ds_write at end of step s+1.
// INM: 0 = fp32 NCHW input, 1 = bf16 NHWC (stride XSTR).
// RES: 0 none, 1 fp32 NCHW, 2 bf16 NHWC stride 180.
// OUTM: 0 fp32 NCHW, 1 bf16 NHWC (stride OSTR).
// ---------------------------------------------------------------------------
template<int CI, int CO, int G, int INM, int XSTR, bool RELU, int RES, int OUTM, int OSTR>
__global__ __launch_bounds__(256, 4) void conv_v5(
    const void* __restrict__ Xv, const u16* __restrict__ Wp,
    const float* __restrict__ bias, const void* __restrict__ Rv,
    void* __restrict__ Yv)
{
    constexpr int CI_PAD = ((CI + 31) / 32) * 32;
    constexpr int NSTEP  = CI_PAD / 32;
    constexpr int LDK    = 40;     // u16 row stride (80 B, 16B-aligned rows)

    __shared__ u16 Xt[2][64 * LDK];

    const int tid  = threadIdx.x;
    const int p0   = blockIdx.x * 64;      // global flat pixel base (incl. batch)
    const int b    = p0 >> 16;
    const int pix0 = p0 & 65535;
    const int h    = pix0 >> 8;
    const int w0c  = pix0 & 255;
    const int lane = tid & 63, wid = tid >> 6;
    const int lr = lane & 15, lg = lane >> 4;
    const int co_wave = blockIdx.y * 192 + wid * 48;

    const float* Xf = (const float*)Xv + (size_t)b * CI * HWSZ;
    const u16*   Xh = (const u16*)Xv;      // NHWC: batch folded into pixel id

    const int xn  = tid & 63;   // pixel within tile this thread stages
    const int k4a = tid >> 6;   // base k-quad (0..3); also handles k4a+4

    auto loadX = [&](int kt, u16x4 (&r)[2]) {
        #pragma unroll
        for (int it = 0; it < 2; ++it) {
            const int k4 = k4a + it * 4;
            const int c0 = kt + k4 * 4;
            u16x4 v = {0, 0, 0, 0};
            if (c0 < CI) {     // quads never straddle CI (4 | CI)
                int dh = 0, dw = 0;
                if (G > 0) {   // 4 | G: shift is quad-uniform
                    const int g = c0 / G;
                    if      (g == 0) dw = 1;
                    else if (g == 1) dw = -1;
                    else if (g == 2) dh = 1;
                    else if (g == 3) dh = -1;
                }
                const int hh = h + dh;
                const int wp = w0c + xn + dw;
                if (hh >= 0 && hh < 256 && wp >= 0 && wp < 256) {
                    if constexpr (INM == 1) {
                        const size_t pg = (size_t)((b << 16) | (hh << 8) | wp);
                        v = *(const u16x4*)&Xh[pg * XSTR + c0];
                    } else {
                        const float* xs = Xf + (size_t)c0 * HWSZ + hh * 256 + wp;
                        #pragma unroll
                        for (int j = 0; j < 4; ++j) v[j] = f2bf(xs[(size_t)j * HWSZ]);
                    }
                }
            }
            r[it] = v;
        }
    };

    auto loadW = [&](int kt, bf16x8 (&a)[3]) {
        #pragma unroll
        for (int mf = 0; mf < 3; ++mf)
            a[mf] = *(const bf16x8*)&Wp[(size_t)(co_wave + mf * 16 + lr) * CI_PAD + kt + lg * 8];
    };

    auto writeLDS = [&](u16x4 (&r)[2], int buf) {
        *(u16x4*)&Xt[buf][xn * LDK + k4a * 4]       = r[0];
        *(u16x4*)&Xt[buf][xn * LDK + (k4a + 4) * 4] = r[1];
    };

    f32x4 acc[3][4] = {};
    u16x4 rawQ[2][2];
    bf16x8 af[2][3];

    loadX(0, rawQ[0]);
    loadW(0, af[0]);
    loadX(32, rawQ[1]);            // NSTEP >= 2 always here
    writeLDS(rawQ[0], 0);          // waits slot-0 loads; slot 0 now free

    #pragma unroll
    for (int s = 0; s < NSTEP; ++s) {
        const int cur = s & 1, nxt = cur ^ 1;
        __syncthreads();                      // Xt[cur] ready for all waves
        if (s + 2 < NSTEP) loadX((s + 2) * 32, rawQ[cur]);   // depth-2 issue
        if (s + 1 < NSTEP) loadW((s + 1) * 32, af[nxt]);     // depth-1 (L2)
        bf16x8 bfr[4];
        #pragma unroll
        for (int nf = 0; nf < 4; ++nf)
            bfr[nf] = *(const bf16x8*)&Xt[cur][(nf * 16 + lr) * LDK + lg * 8];
        #pragma unroll
        for (int mf = 0; mf < 3; ++mf)
            #pragma unroll
            for (int nf = 0; nf < 4; ++nf)
                acc[mf][nf] = __builtin_amdgcn_mfma_f32_16x16x32_bf16(
                    af[cur][mf], bfr[nf], acc[mf][nf], 0, 0, 0);
        if (s + 1 < NSTEP) writeLDS(rawQ[nxt], nxt);  // waits loads from step s-1
    }

    // ---- epilogue: co = co_wave + mf*16 + lg*4 + r, pixel col = lr
    const float* Rf = (const float*)Rv;
    const u16*   Rh = (const u16*)Rv;
    #pragma unroll
    for (int mf = 0; mf < 3; ++mf) {
        const int co_b = co_wave + mf * 16 + lg * 4;
        if (co_b >= CO) continue;
        #pragma unroll
        for (int nf = 0; nf < 4; ++nf) {
            const int pl = pix0 + nf * 16 + lr;          // pixel within batch
            const size_t pg = (size_t)p0 + nf * 16 + lr; // global flat pixel
            float v[4];
            #pragma unroll
            for (int r = 0; r < 4; ++r) {
                v[r] = acc[mf][nf][r] + bias[co_b + r];
                if (RELU) v[r] = fmaxf(v[r], 0.f);
            }
            if (RES == 1) {
                #pragma unroll
                for (int r = 0; r < 4; ++r)
                    v[r] += Rf[((size_t)(b * CO + co_b + r)) * HWSZ + pl];
            }
            if (RES == 2) {
                u16x4 rr = *(const u16x4*)&Rh[pg * 180 + co_b];
                #pragma unroll
                for (int r = 0; r < 4; ++r) v[r] += bf2f(rr[r]);
            }
            if (OUTM == 1) {
                u16x4 o;
                #pragma unroll
                for (int r = 0; r < 4; ++r) o[r] = f2bf(v[r]);
                *(u16x4*)&((u16*)Yv)[pg * OSTR + co_b] = o;
            } else {
                #pragma unroll
                for (int r = 0; r < 4; ++r)
                    ((float*)Yv)[((size_t)(b * CO + co_b + r)) * HWSZ + pl] = v[r];
            }
        }
    }
}

// ---------------------------------------------------------------------------
// BN stats on NHWC zt (stride 360), stage 1. part: [512][45][16]
// ---------------------------------------------------------------------------
__global__ __launch_bounds__(256) void bn_part(const u16* __restrict__ zt,
                                               float* __restrict__ part)
{
    const int tid = threadIdx.x;
    const int oc  = tid & 63;        // channel octet (0..44 active)
    const int pp  = tid >> 6;        // 0..3
    if (oc >= 45) return;
    const int stripe = blockIdx.x * 4 + pp;
    const int pb = blockIdx.x * 1024 + pp;
    float s[8] = {}, q[8] = {};
    for (int i = 0; i < 256; ++i) {
        const int p = pb + i * 4;
        u16x8 t = *(const u16x8*)&zt[(size_t)p * 360 + oc * 8];
        #pragma unroll
        for (int j = 0; j < 8; ++j) {
            float v = bf2f(t[j]);
            s[j] += v; q[j] += v * v;
        }
    }
    float* pr = part + ((size_t)stripe * 45 + oc) * 16;
    #pragma unroll
    for (int j = 0; j < 8; ++j) { pr[j] = s[j]; pr[8 + j] = q[j]; }
}

// BN stats, stage 2: reduce 512 stripes -> fused scale/shift. grid 45.
__global__ __launch_bounds__(256) void bn_fin(const float* __restrict__ part,
                                              const float* __restrict__ g,
                                              const float* __restrict__ bb,
                                              float* __restrict__ sc,
                                              float* __restrict__ sh)
{
    const int oc = blockIdx.x;   // 0..44
    const int t  = threadIdx.x;
    const float* p1 = part + ((size_t)t * 45 + oc) * 16;
    const float* p2 = part + ((size_t)(t + 256) * 45 + oc) * 16;
    float v[16];
    #pragma unroll
    for (int k = 0; k < 16; ++k) v[k] = p1[k] + p2[k];
    #pragma unroll
    for (int k = 0; k < 16; ++k)
        for (int m = 32; m; m >>= 1) v[k] += __shfl_xor(v[k], m, 64);
    __shared__ float red[4][16];
    if ((t & 63) == 0) {
        #pragma unroll
        for (int k = 0; k < 16; ++k) red[t >> 6][k] = v[k];
    }
    __syncthreads();
    if (t == 0) {
        const float invN = 1.f / (float)NPIX;
        #pragma unroll
        for (int j = 0; j < 8; ++j) {
            const int c = oc * 8 + j;
            float su = red[0][j] + red[1][j] + red[2][j] + red[3][j];
            float sq = red[0][8+j] + red[1][8+j] + red[2][8+j] + red[3][8+j];
            float mean = su * invN;
            float var  = sq * invN - mean * mean;
            float istd = 1.f / sqrtf(var + 1e-5f);
            float s = g[c] * istd;
            sc[c] = s;
            sh[c] = bb[c] - mean * s;
        }
    }
}

// ---------------------------------------------------------------------------
// Windowed self-attention, NHWC bf16 in (stride 360) / out (stride 180).
// ---------------------------------------------------------------------------
template<int WS>
__global__ __launch_bounds__(256) void attn_v2(
    const u16* __restrict__ zt, const float* __restrict__ scale,
    const float* __restrict__ shiftc, u16* __restrict__ ot, int chunk)
{
    constexpr int NP  = WS * WS;
    constexpr int GPB = 256 / NP;
    constexpr int SH  = WS / 2;
    constexpr int NW  = 256 / WS;

    __shared__ float qs[256 * 12];
    __shared__ float vs[256 * 12];

    const int tid = threadIdx.x;
    const int lg  = tid / NP;
    const int n   = tid % NP;
    const int gidx = blockIdx.x * GPB + lg;

    const int head = gidx % 6;
    const int win  = gidx / 6;
    const int wcol = win % NW;
    const int tmp  = win / NW;
    const int wrow = tmp % NW;
    const int b    = tmp / NW;

    const int i = n / WS, j = n % WS;
    const int hh = (wrow * WS + i + SH) & 255;
    const int ww = (wcol * WS + j + SH) & 255;
    const size_t zrow = (size_t)((b << 16) | (hh << 8) | ww) * 360;

    const int cq = chunk * 120 + head * 10;
    const int cv = cq + 60;

    float q[10];
    float* qrow = &qs[tid * 12];
    float* vrow = &vs[tid * 12];
    #pragma unroll
    for (int c2 = 0; c2 < 5; ++c2) {
        u16x2 uq = *(const u16x2*)&zt[zrow + cq + c2 * 2];
        u16x2 uv = *(const u16x2*)&zt[zrow + cv + c2 * 2];
        float q0 = bf2f(uq[0]) * scale[cq + c2 * 2]     + shiftc[cq + c2 * 2];
        float q1 = bf2f(uq[1]) * scale[cq + c2 * 2 + 1] + shiftc[cq + c2 * 2 + 1];
        float v0 = bf2f(uv[0]) * scale[cv + c2 * 2]     + shiftc[cv + c2 * 2];
        float v1 = bf2f(uv[1]) * scale[cv + c2 * 2 + 1] + shiftc[cv + c2 * 2 + 1];
        q[c2 * 2] = q0; q[c2 * 2 + 1] = q1;
        qrow[c2 * 2] = q0; qrow[c2 * 2 + 1] = q1;
        vrow[c2 * 2] = v0; vrow[c2 * 2 + 1] = v1;
    }
    qrow[10] = 0.f; qrow[11] = 0.f;
    vrow[10] = 0.f; vrow[11] = 0.f;
    __syncthreads();

    const float* qg = &qs[(lg * NP) * 12];
    const float* vg = &vs[(lg * NP) * 12];

    float mx = -1e30f;
    for (int m = 0; m < NP; ++m) {
        f32x4 a0 = *(const f32x4*)&qg[m * 12];
        f32x4 a1 = *(const f32x4*)&qg[m * 12 + 4];
        f32x4 a2 = *(const f32x4*)&qg[m * 12 + 8];
        float d = q[0]*a0[0] + q[1]*a0[1] + q[2]*a0[2] + q[3]*a0[3]
                + q[4]*a1[0] + q[5]*a1[1] + q[6]*a1[2] + q[7]*a1[3]
                + q[8]*a2[0] + q[9]*a2[1];
        mx = fmaxf(mx, d);
    }
    float s = 0.f;
    float o[10] = {};
    for (int m = 0; m < NP; ++m) {
        f32x4 a0 = *(const f32x4*)&qg[m * 12];
        f32x4 a1 = *(const f32x4*)&qg[m * 12 + 4];
        f32x4 a2 = *(const f32x4*)&qg[m * 12 + 8];
        float d = q[0]*a0[0] + q[1]*a0[1] + q[2]*a0[2] + q[3]*a0[3]
                + q[4]*a1[0] + q[5]*a1[1] + q[6]*a1[2] + q[7]*a1[3]
                + q[8]*a2[0] + q[9]*a2[1];
        float e = __expf(d - mx);
        s += e;
        f32x4 b0 = *(const f32x4*)&vg[m * 12];
        f32x4 b1 = *(const f32x4*)&vg[m * 12 + 4];
        f32x4 b2 = *(const f32x4*)&vg[m * 12 + 8];
        o[0] += e * b0[0]; o[1] += e * b0[1]; o[2] += e * b0[2]; o[3] += e * b0[3];
        o[4] += e * b1[0]; o[5] += e * b1[1]; o[6] += e * b1[2]; o[7] += e * b1[3];
        o[8] += e * b2[0]; o[9] += e * b2[1];
    }
    const float inv = 1.f / s;
    u16* orow = ot + (size_t)((b << 16) | (hh << 8) | ww) * 180 + chunk * 60 + head * 10;
    #pragma unroll
    for (int c2 = 0; c2 < 5; ++c2) {
        u16x2 ov;
        ov[0] = f2bf(o[c2 * 2] * inv);
        ov[1] = f2bf(o[c2 * 2 + 1] * inv);
        *(u16x2*)&orow[c2 * 2] = ov;
    }
}

// ---------------------------------------------------------------------------
extern "C" void kernel_launch(void* const* d_in, const int* in_sizes, int n_in,
                              void* d_out, int out_size, void* d_ws, size_t ws_size,
                              hipStream_t stream)
{
    const float* x     = (const float*)d_in[0];
    const float* w0    = (const float*)d_in[1];
    const float* b0    = (const float*)d_in[2];
    const float* w1    = (const float*)d_in[3];
    const float* b1    = (const float*)d_in[4];
    const float* w_in  = (const float*)d_in[5];
    const float* b_in  = (const float*)d_in[6];
    const float* bn_g  = (const float*)d_in[7];
    const float* bn_b  = (const float*)d_in[8];
    const float* w_out = (const float*)d_in[9];
    const float* b_out = (const float*)d_in[10];
    float* out = (float*)d_out;

    // workspace: NHWC bf16 (unpadded strides). zt aliases y (y dead after conv2)
    u16* y   = (u16*)d_ws;                      // [131072][360] (later zt)
    u16* x1b = y   + (size_t)NPIX * 360;        // [131072][180]
    u16* ot  = x1b + (size_t)NPIX * 180;        // [131072][180]
    u16* W0p = ot  + (size_t)NPIX * 180;        // 384x192
    u16* Wip = W0p + 384 * 192;                 // 384x192
    u16* W1p = Wip + 384 * 192;                 // 192x384
    u16* Wop = W1p + 192 * 384;                 // 192x192
    float* part   = (float*)(Wop + 192 * 192);  // 512*45*16
    float* scale  = part + 512 * 45 * 16;
    float* shiftc = scale + 360;
    u16* zt = y;

    dim3 blk(256);

    prep_w<<<dim3(288), blk, 0, stream>>>(w0, w1, w_in, w_out, W0p, W1p, Wip, Wop);

    // conv1: y = relu(W0 @ shift(x) + b0)     x fp32 NCHW -> y NHWC360
    conv_v5<180, 360, 36, 0, 0,   true,  0, 1, 360>
        <<<dim3(2048, 2), blk, 0, stream>>>(x, W0p, b0, nullptr, y);
    // conv2: x1 = W1 @ shift(y) + b1 + x      y NHWC360, resid x fp32 -> x1b NHWC180
    conv_v5<360, 180, 72, 1, 360, false, 1, 1, 180>
        <<<dim3(2048, 1), blk, 0, stream>>>(y, W1p, b1, x, x1b);
    // conv3: z = W_in @ x1 + b_in             x1b NHWC180 -> zt NHWC360 (aliases y)
    conv_v5<180, 360, 0,  1, 180, false, 0, 1, 360>
        <<<dim3(2048, 2), blk, 0, stream>>>(x1b, Wip, b_in, nullptr, zt);
    // BN statistics -> fused scale/shift
    bn_part<<<dim3(128), blk, 0, stream>>>(zt, part);
    bn_fin<<<dim3(45), blk, 0, stream>>>(part, bn_g, bn_b, scale, shiftc);
    // window attention, chunks 0/1/2 with ws = 2/4/8 -> ot NHWC180
    attn_v2<2><<<dim3(3072), blk, 0, stream>>>(zt, scale, shiftc, ot, 0);
    attn_v2<4><<<dim3(3072), blk, 0, stream>>>(zt, scale, shiftc, ot, 1);
    attn_v2<8><<<dim3(3072), blk, 0, stream>>>(zt, scale, shiftc, ot, 2);
    // conv4: out = W_out @ ot + b_out + x1    ot NHWC180, resid x1b -> out fp32 NCHW
    conv_v5<180, 180, 0,  1, 180, false, 2, 0, 0>
        <<<dim3(2048, 1), blk, 0, stream>>>(ot, Wop, b_out, x1b, out);
}